// Round 4
// baseline (128.687 us; speedup 1.0000x reference)
//
#include <hip/hip_runtime.h>
#include <hip/hip_bf16.h>
#include <stdint.h>

#define BATCH 8
#define SEQN  4096
#define DIM   128

typedef __attribute__((ext_vector_type(16))) float f32x16;
typedef __bf16 bf16x8 __attribute__((ext_vector_type(8)));

#define GAS __attribute__((address_space(1)))
#define LAS __attribute__((address_space(3)))

__device__ __forceinline__ ushort f2b(float x) {
  union { float f; uint32_t u; } a; a.f = x;
  uint32_t r = a.u + 0x7fffu + ((a.u >> 16) & 1u);   // RNE
  return (ushort)(r >> 16);
}
__device__ __forceinline__ uint32_t pkbf(float a, float b) {
  union { __bf16 h[2]; uint32_t u; } x;
  x.h[0] = (__bf16)a; x.h[1] = (__bf16)b;
  return x.u;
}

// Fragment-major layouts, per 32-row chunk g (global row/32), 4096 elems/chunk:
//   Q/K: slot = (kc*2+hi)*32 + ql holds  X[g*32+ql][16*kc+8*hi + 0..7]
//   V^T: slot = (db*4+ks*2+hi)*32 + ql holds V[g*32 + 16*ks+8*hi + 0..7][32*db+ql]

// ---- prep_qk: rnorm + bf16 + fragment-major writeout (Q plain, K' scaled) ----
__global__ __launch_bounds__(256) void prep_qk(
    const float* __restrict__ qk, ushort* __restrict__ qfb, ushort* __restrict__ kfb) {
  __shared__ ushort qt_l[32 * 136];
  __shared__ ushort kt_l[32 * 136];
  const int g = blockIdx.x;
  const int t = threadIdx.x;
  const int r = t >> 3, s = t & 7;
  const float* src = qk + (size_t)g * 4096 + r * 128 + s * 16;
  float x[16];
  #pragma unroll
  for (int i = 0; i < 4; ++i) {
    float4 f = ((const float4*)src)[i];
    x[4*i] = f.x; x[4*i+1] = f.y; x[4*i+2] = f.z; x[4*i+3] = f.w;
  }
  float ss = 0.f;
  #pragma unroll
  for (int i = 0; i < 16; ++i) ss += x[i] * x[i];
  ss += __shfl_xor(ss, 1, 64);
  ss += __shfl_xor(ss, 2, 64);
  ss += __shfl_xor(ss, 4, 64);
  float rn = 1.0f / fmaxf(sqrtf(ss), 1e-12f);
  const float SC = 1.44269504088896340736f / 11.313708498984761f; // log2e/sqrt(128)
  float rs = rn * SC;
  #pragma unroll
  for (int j = 0; j < 16; ++j) {
    qt_l[r * 136 + s * 16 + j] = f2b(x[j]);
    kt_l[r * 136 + s * 16 + j] = f2b(x[j] * rs);
  }
  __syncthreads();
  #pragma unroll
  for (int p = 0; p < 2; ++p) {
    int sl = t + 256 * p;
    int qli = sl & 31, grp = sl >> 5;
    union { ushort u[8]; int4 v; } tq, tk;
    #pragma unroll
    for (int j = 0; j < 8; ++j) {
      tq.u[j] = qt_l[qli * 136 + grp * 8 + j];
      tk.u[j] = kt_l[qli * 136 + grp * 8 + j];
    }
    *(int4*)(qfb + (size_t)g * 4096 + sl * 8) = tq.v;
    *(int4*)(kfb + (size_t)g * 4096 + sl * 8) = tk.v;
  }
}

// ---- prep_v: bf16 + transposed fragment-major writeout ----
__global__ __launch_bounds__(256) void prep_v(
    const float* __restrict__ v, ushort* __restrict__ vfb) {
  __shared__ ushort vt_l[32 * 136];
  const int g = blockIdx.x;
  const int t = threadIdx.x;
  const int r = t >> 3, s = t & 7;
  const float* src = v + (size_t)g * 4096 + r * 128 + s * 16;
  #pragma unroll
  for (int i = 0; i < 4; ++i) {
    float4 f = ((const float4*)src)[i];
    vt_l[r * 136 + s * 16 + 4*i]     = f2b(f.x);
    vt_l[r * 136 + s * 16 + 4*i + 1] = f2b(f.y);
    vt_l[r * 136 + s * 16 + 4*i + 2] = f2b(f.z);
    vt_l[r * 136 + s * 16 + 4*i + 3] = f2b(f.w);
  }
  __syncthreads();
  #pragma unroll
  for (int p = 0; p < 2; ++p) {
    int sl = t + 256 * p;
    int qli = sl & 31, grp = sl >> 5;
    int db = grp >> 2, ks = (grp >> 1) & 1, hh = grp & 1;
    union { ushort u[8]; int4 v; } tv;
    #pragma unroll
    for (int j = 0; j < 8; ++j)
      tv.u[j] = vt_l[(16 * ks + 8 * hh + j) * 136 + 32 * db + qli];
    *(int4*)(vfb + (size_t)g * 4096 + sl * 8) = tv.v;
  }
}

// ---- attn: 8 waves = 2 qc x 4 hf; K direct from L2; V dbuf LDS; Q in LDS ----
__global__ __launch_bounds__(512, 4) void attn_kernel(
    const ushort* __restrict__ qfb, const ushort* __restrict__ kfb,
    const ushort* __restrict__ vfb, float* __restrict__ out) {
  __shared__ ushort lds[40960];  // 80KB: V [0,65536)B dbuf, Q [65536,81920)B

  const int tid = threadIdx.x;
  const int w  = tid >> 6;
  const int l  = tid & 63;
  const int ql = l & 31;
  const int hi = l >> 5;
  const int qc = w & 1;
  const int hf = w >> 1;

  const int bidx  = blockIdx.x;
  const int batch = bidx & 7;             // XCD b holds batch b's KV in its L2
  const int qt    = bidx >> 3;            // 0..63
  const int q0    = qt * 64 + qc * 32;    // in-batch q base for this wave
  const size_t qpb   = ((size_t)batch * 128 + qt * 2) * 4096;  // Q chunk pair
  const size_t kvch0 = (size_t)batch * 128 + hf * 32;          // kv chunk base

  // ---- stage Q (16KB, both chunks, linear) ----
  {
    const ushort* qsrc = qfb + qpb + w * 1024 + l * 8;
    #pragma unroll
    for (int i = 0; i < 2; ++i)
      __builtin_amdgcn_global_load_lds((const GAS uint32_t*)(qsrc + i * 512),
          (LAS uint32_t*)(lds + (65536 + w * 2048 + i * 1024) / 2), 16, 0, 0);
  }

#define STAGE(bsel, t_) do {                                                   \
    const ushort* vsrc_ = vfb + (kvch0 + (t_)) * 4096 + qc * 2048 + l * 8;     \
    _Pragma("unroll")                                                          \
    for (int i_ = 0; i_ < 4; ++i_)                                             \
      __builtin_amdgcn_global_load_lds((const GAS uint32_t*)(vsrc_ + i_ * 512),\
          (LAS uint32_t*)(lds + ((bsel) * 32768 + hf * 8192 + qc * 4096 +      \
                                 i_ * 1024) / 2), 16, 0, 0);                   \
  } while (0)

  STAGE(0, 0);
  asm volatile("s_waitcnt vmcnt(0)" ::: "memory");
  __syncthreads();

  f32x16 o[4];
  #pragma unroll
  for (int db = 0; db < 4; ++db)
    #pragma unroll
    for (int r = 0; r < 16; ++r) o[db][r] = 0.f;
  float m = -INFINITY, lsum = 0.f;

  int buf = 0;
  for (int t = 0; t < 32; ++t) {
    if (t + 1 < 32) STAGE(buf ^ 1, t + 1);

    // ---- K fragments straight from global (L2/L1-resident, coalesced) ----
    const ushort* kt_p = kfb + (kvch0 + t) * 4096 + l * 8;
    bf16x8 kf[8];
    #pragma unroll
    for (int kc = 0; kc < 8; ++kc) kf[kc] = *(const bf16x8*)(kt_p + kc * 512);

    // ---- S^T = K * Q^T (Q frags from LDS, lane-linear) ----
    f32x16 st;
    #pragma unroll
    for (int r = 0; r < 16; ++r) st[r] = 0.f;
    const ushort* qlp = lds + (32768 + qc * 4096) + l * 8;
    __builtin_amdgcn_s_setprio(1);
    #pragma unroll
    for (int kc = 0; kc < 8; ++kc) {
      bf16x8 qf = *(const bf16x8*)(qlp + kc * 512);
      st = __builtin_amdgcn_mfma_f32_32x32x16_bf16(kf[kc], qf, st, 0, 0, 0);
    }
    __builtin_amdgcn_s_setprio(0);

    // ---- diagonal mask ----
    const int kv0g = hf * 1024 + t * 32;
    if (kv0g == q0) {
      #pragma unroll
      for (int r = 0; r < 16; ++r) {
        int crow = (r & 3) + 8 * (r >> 2) + 4 * hi;
        if (crow == ql) st[r] = -1e30f;
      }
    }

    // ---- online softmax (lane owns q-row q0+ql) ----
    float pm = st[0];
    #pragma unroll
    for (int r = 1; r < 16; ++r) pm = fmaxf(pm, st[r]);
    pm = fmaxf(pm, __shfl_xor(pm, 32, 64));
    if (__any(pm > m + 8.0f)) {          // T13 defer-max
      float mn = fmaxf(m, pm);
      float sc0 = exp2f(m - mn);
      m = mn; lsum *= sc0;
      #pragma unroll
      for (int db = 0; db < 4; ++db)
        #pragma unroll
        for (int r = 0; r < 16; ++r) o[db][r] *= sc0;
    }
    float rs_ = 0.f;
    #pragma unroll
    for (int r = 0; r < 16; ++r) {
      float p = exp2f(st[r] - m);
      st[r] = p;
      rs_ += p;
    }
    rs_ += __shfl_xor(rs_, 32, 64);
    lsum += rs_;

    // ---- pack P -> bf16, quad exchange across halves ----
    uint32_t ww[4][2];
    #pragma unroll
    for (int q4 = 0; q4 < 4; ++q4) {
      ww[q4][0] = pkbf(st[4 * q4 + 0], st[4 * q4 + 1]);
      ww[q4][1] = pkbf(st[4 * q4 + 2], st[4 * q4 + 3]);
    }
    bf16x8 pa[2];
    #pragma unroll
    for (int ks = 0; ks < 2; ++ks) {
      uint32_t ow0 = hi ? ww[2*ks+1][0] : ww[2*ks][0];
      uint32_t ow1 = hi ? ww[2*ks+1][1] : ww[2*ks][1];
      uint32_t sv0 = hi ? ww[2*ks][0]   : ww[2*ks+1][0];
      uint32_t sv1 = hi ? ww[2*ks][1]   : ww[2*ks+1][1];
      uint32_t rv0 = (uint32_t)__shfl_xor((int)sv0, 32, 64);
      uint32_t rv1 = (uint32_t)__shfl_xor((int)sv1, 32, 64);
      union { uint32_t u[4]; bf16x8 v; } pb;
      pb.u[0] = hi ? rv0 : ow0;
      pb.u[1] = hi ? rv1 : ow1;
      pb.u[2] = hi ? ow0 : rv0;
      pb.u[3] = hi ? ow1 : rv1;
      pa[ks] = pb.v;
    }

    // ---- O^T += V^T * P^T (V frags lane-linear from LDS) ----
    const ushort* vlp = lds + (buf * 16384 + hf * 4096) + l * 8;
    __builtin_amdgcn_s_setprio(1);
    #pragma unroll
    for (int db = 0; db < 4; ++db)
      #pragma unroll
      for (int ks = 0; ks < 2; ++ks) {
        bf16x8 vv = *(const bf16x8*)(vlp + (db * 4 + ks * 2) * 256);
        o[db] = __builtin_amdgcn_mfma_f32_32x32x16_bf16(vv, pa[ks], o[db], 0, 0, 0);
      }
    __builtin_amdgcn_s_setprio(0);

    asm volatile("s_waitcnt vmcnt(0)" ::: "memory");
    __syncthreads();
    buf ^= 1;
  }
#undef STAGE

  // ---- 4-way KV combine (tree: hf3/hf1 write, hf2/hf0 add, hf0 final) ----
  float* flds = (float*)lds;
  if (hi == 0) { flds[w * 64 + ql] = m; flds[w * 64 + 32 + ql] = lsum; }
  __syncthreads();
  float M = -INFINITY, mi4[4];
  #pragma unroll
  for (int i = 0; i < 4; ++i) {
    mi4[i] = flds[(qc + 2 * i) * 64 + ql];
    M = fmaxf(M, mi4[i]);
  }
  float L = 0.f;
  #pragma unroll
  for (int i = 0; i < 4; ++i)
    L += flds[(qc + 2 * i) * 64 + 32 + ql] * exp2f(mi4[i] - M);
  const float sc = exp2f(m - M);
  float* oA = flds + 512 + qc * 8704;   // [128][34]
  float* oB = oA + 4352;

  if (hf == 3 || hf == 1) {
    float* dst = (hf == 3) ? oA : oB;
    #pragma unroll
    for (int db = 0; db < 4; ++db)
      #pragma unroll
      for (int r = 0; r < 16; ++r) {
        int crow = (r & 3) + 8 * (r >> 2) + 4 * hi;
        dst[(32 * db + crow) * 34 + ql] = o[db][r] * sc;
      }
  }
  __syncthreads();
  if (hf == 2 || hf == 0) {
    float* dst = (hf == 2) ? oA : oB;
    #pragma unroll
    for (int db = 0; db < 4; ++db)
      #pragma unroll
      for (int r = 0; r < 16; ++r) {
        int crow = (r & 3) + 8 * (r >> 2) + 4 * hi;
        dst[(32 * db + crow) * 34 + ql] += o[db][r] * sc;
      }
  }
  __syncthreads();
  if (hf == 0) {
    const float inv = 1.0f / L;
    float* epw = flds + 17920 + qc * 1088;
    float* outb = out + (size_t)batch * SEQN * DIM;
    #pragma unroll
    for (int db = 0; db < 4; ++db) {
      float fin[16];
      #pragma unroll
      for (int r = 0; r < 16; ++r) {
        int crow = (r & 3) + 8 * (r >> 2) + 4 * hi;
        int idx = (32 * db + crow) * 34 + ql;
        fin[r] = (oA[idx] + oB[idx]) * inv;
      }
      #pragma unroll
      for (int rr = 0; rr < 8; ++rr) {
        int r0 = 2 * rr;
        int crow = (r0 & 3) + 8 * (r0 >> 2) + 4 * hi;
        *(float2*)(epw + ql * 34 + crow) = make_float2(fin[r0], fin[r0 + 1]);
      }
      __builtin_amdgcn_s_waitcnt(0);
      #pragma unroll
      for (int s2 = 0; s2 < 8; ++s2) {
        int row = 4 * s2 + (l >> 4);
        int c2  = l & 15;
        float2 v2 = *(const float2*)(epw + row * 34 + 2 * c2);
        *(float2*)(outb + (size_t)(q0 + row) * DIM + 32 * db + 2 * c2) = v2;
      }
      __builtin_amdgcn_s_waitcnt(0);
    }
  }
}

extern "C" void kernel_launch(void* const* d_in, const int* in_sizes, int n_in,
                              void* d_out, int out_size, void* d_ws, size_t ws_size,
                              hipStream_t stream) {
  (void)in_sizes; (void)n_in; (void)out_size; (void)ws_size;
  const float* qk = (const float*)d_in[0];
  const float* v  = (const float*)d_in[1];
  float* out = (float*)d_out;
  size_t nelem = (size_t)BATCH * SEQN * DIM;
  ushort* qfb = (ushort*)d_ws;
  ushort* kfb = qfb + nelem;
  ushort* vfb = kfb + nelem;
  prep_qk<<<BATCH * SEQN / 32, 256, 0, stream>>>(qk, qfb, kfb);
  prep_v <<<BATCH * SEQN / 32, 256, 0, stream>>>(v, vfb);
  attn_kernel<<<BATCH * (SEQN / 64), 512, 0, stream>>>(qfb, kfb, vfb, out);
}